// Round 5
// baseline (155.282 us; speedup 1.0000x reference)
//
#include <hip/hip_runtime.h>

#define EPS 1e-5f

typedef float f2 __attribute__((ext_vector_type(2)));
typedef float f4 __attribute__((ext_vector_type(4)));

// Broadcast a block-uniform load into an SGPR (scalars).
__device__ __forceinline__ float uload(const float* __restrict__ p) {
  return __int_as_float(__builtin_amdgcn_readfirstlane(__float_as_int(*p)));
}

// ---------------------------------------------------------------------------
// K12: fused conv1(1->8)+ReLU+pool + conv2(4 used oc of 16)+ReLU+pool + sum.
// Block = (batch b, quarter q): pooled2 rows 8q..8q+7, 256 threads.
// Structure learned across rounds:
//  - conv1 reads x from GLOBAL (r3: conflict-free, L1-served). r4's LDS xtile
//    stride-2 reads cost 1.06M conflict cycles — never again.
//  - p1 (pooled1) in LDS only, split into two 4-channel passes so LDS stays
//    ~21 KB -> 6 blocks/CU (launch_bounds(256,6)) vs r3's 4.
//  - weights staged once in LDS padded to stride 12 -> uniform ds_read_b128
//    broadcasts (3 reads / 9 weights) instead of 288 uload+readfirstlane.
//  - conv1 thread handles 2 adjacent pooled cols: 4x6 window = f4 + 2 clamped
//    scalars per row (6 loads + 6 cndmask per position vs r3's 16+32).
// ---------------------------------------------------------------------------
__global__ __launch_bounds__(256, 6) void k12_fused(
    const float* __restrict__ x, const float* __restrict__ w1,
    const float* __restrict__ b1, const float* __restrict__ w2,
    const float* __restrict__ b2, float* __restrict__ partials) {
  __shared__ float p1[4][18][66];  // one 4-channel group; col idx = col+1
  __shared__ float w1s[104];       // [oc][12]: k0..8, bias at [oc*12+9]
  __shared__ float w2s[392];       // [(oc*8+ic)][12] (384) + b2[4] at 384..
  __shared__ float wred[4][4];

  const int q   = blockIdx.x & 3;
  const int b   = blockIdx.x >> 2;
  const int tid = threadIdx.x;
  const float* xb = x + (size_t)b * (128 * 128);

  // ---- stage weights, padded 9 -> 12 for aligned b128 broadcast reads ----
  if (tid < 72) w1s[(tid / 9) * 12 + tid % 9] = w1[tid];
  if (tid >= 72 && tid < 80) w1s[(tid - 72) * 12 + 9] = b1[tid - 72];
  {
    int t = tid;                      // first 288 floats of w2 = oc 0..3
    w2s[(t / 9) * 12 + t % 9] = w2[t];
    t = tid + 256;
    if (t < 288) w2s[(t / 9) * 12 + t % 9] = w2[t];
  }
  if (tid < 4) w2s[384 + tid] = b2[tid];
  // zero p1's SAME-padding halo columns (constant across both passes)
  if (tid < 72) {
    int ic = tid / 18, r = tid % 18;
    p1[ic][r][0]  = 0.f;
    p1[ic][r][65] = 0.f;
  }
  __syncthreads();

  const int px2  = tid & 31;
  const int py2l = tid >> 5;  // 0..7

  // conv2 accumulators (bias-init once; accumulate across both passes)
  float acc[4][2][2];
#pragma unroll
  for (int oc = 0; oc < 4; ++oc) {
    float bias = w2s[384 + oc];
    acc[oc][0][0] = bias; acc[oc][0][1] = bias;
    acc[oc][1][0] = bias; acc[oc][1][1] = bias;
  }

#pragma unroll 1
  for (int g = 0; g < 2; ++g) {
    if (g) __syncthreads();  // pass-0 conv2 reads done before p1 overwrite

    // ---- conv1 + ReLU + pool for channels 4g..4g+3 -> p1 ----
    // window = (gl, col pair i): pooled cols 2i,2i+1 share a 4x6 x-window.
#pragma unroll 1
    for (int pos = tid; pos < 576; pos += 256) {
      const int gl = pos >> 5, i = pos & 31;
      const int G  = 16 * q - 1 + gl;
      const bool vG = ((unsigned)G) < 64u;
      const int xr0 = 2 * G - 1;
      float xin[4][6];  // x cols 4i-1 .. 4i+4, rows xr0..xr0+3 (clamped)
#pragma unroll
      for (int r = 0; r < 4; ++r) {
        const int row  = xr0 + r;
        const bool rok = vG && ((unsigned)row < 128u);
        const int rowc = min(max(row, 0), 127);
        const float* rp = xb + rowc * 128;
        const float le = rp[(i == 0) ? 0 : (4 * i - 1)];
        const f4 mid   = *(const f4*)(rp + 4 * i);        // 16B-aligned
        const float ri = rp[(i == 31) ? 127 : (4 * i + 4)];
        xin[r][0] = (rok && i != 0)  ? le    : 0.f;
        xin[r][1] = rok              ? mid.x : 0.f;
        xin[r][2] = rok              ? mid.y : 0.f;
        xin[r][3] = rok              ? mid.z : 0.f;
        xin[r][4] = rok              ? mid.w : 0.f;
        xin[r][5] = (rok && i != 31) ? ri    : 0.f;
      }
#pragma unroll
      for (int oc = 0; oc < 4; ++oc) {
        const int o = 4 * g + oc;
        const f4 wA = *(const f4*)&w1s[o * 12];
        const f4 wB = *(const f4*)&w1s[o * 12 + 4];
        const f2 wC = *(const f2*)&w1s[o * 12 + 8];  // (w8, bias)
        const float wv[9] = {wA.x, wA.y, wA.z, wA.w, wB.x, wB.y, wB.z, wB.w, wC.x};
#pragma unroll
        for (int h = 0; h < 2; ++h) {  // pooled col 2i+h
          float best = 0.f;            // ReLU floor
#pragma unroll
          for (int dy = 0; dy < 2; ++dy)
#pragma unroll
            for (int dx = 0; dx < 2; ++dx) {
              float a = wC.y;
#pragma unroll
              for (int ky = 0; ky < 3; ++ky)
#pragma unroll
                for (int kx = 0; kx < 3; ++kx)
                  a = fmaf(xin[dy + ky][2 * h + dx + kx], wv[ky * 3 + kx], a);
              best = fmaxf(best, a);
            }
          p1[oc][gl][2 * i + 1 + h] = vG ? best : 0.f;
        }
      }
    }
    __syncthreads();

    // ---- conv2 partial: ic 4g..4g+3, all 4 needed oc ----
#pragma unroll 1
    for (int ic = 0; ic < 4; ++ic) {
      float xin[4][4];
#pragma unroll
      for (int r = 0; r < 4; ++r) {
        // even 8B-aligned float2 reads — measured ~0 conflicts in r3
        const f2* rp = (const f2*)&p1[ic][2 * py2l + r][2 * px2];
        f2 v0 = rp[0], v1 = rp[1];
        xin[r][0] = v0.x; xin[r][1] = v0.y; xin[r][2] = v1.x; xin[r][3] = v1.y;
      }
#pragma unroll
      for (int oc = 0; oc < 4; ++oc) {
        const int wi = (oc * 8 + 4 * g + ic) * 12;
        const f4 wA = *(const f4*)&w2s[wi];
        const f4 wB = *(const f4*)&w2s[wi + 4];
        const float w8 = w2s[wi + 8];
        const float wv[9] = {wA.x, wA.y, wA.z, wA.w, wB.x, wB.y, wB.z, wB.w, w8};
#pragma unroll
        for (int dy = 0; dy < 2; ++dy)
#pragma unroll
          for (int dx = 0; dx < 2; ++dx) {
#pragma unroll
            for (int ky = 0; ky < 3; ++ky)
#pragma unroll
              for (int kx = 0; kx < 3; ++kx)
                acc[oc][dy][dx] =
                    fmaf(xin[dy + ky][dx + kx], wv[ky * 3 + kx], acc[oc][dy][dx]);
          }
      }
    }
  }

  // ---- ReLU + 2x2 pool + spatial partial-sum ----
  const int lane = tid & 63, w = tid >> 6;
#pragma unroll
  for (int oc = 0; oc < 4; ++oc) {
    float p = fmaxf(fmaxf(fmaxf(acc[oc][0][0], acc[oc][0][1]),
                          fmaxf(acc[oc][1][0], acc[oc][1][1])), 0.f);
#pragma unroll
    for (int off = 32; off > 0; off >>= 1) p += __shfl_down(p, off);
    if (lane == 0) wred[w][oc] = p;
  }
  __syncthreads();
  if (tid < 4) {
    float s = wred[0][tid] + wred[1][tid] + wred[2][tid] + wred[3][tid];
    partials[((size_t)b * 4 + q) * 4 + tid] = s;
  }
}

// ---------------------------------------------------------------------------
// K3: feats -> quantum circuit -> batchnorm (over batch=512) -> head.
// Single block, 512 threads; thread = batch element. Shuffle reductions.
// ---------------------------------------------------------------------------
__global__ __launch_bounds__(512) void k3_tail(
    const float* __restrict__ partials, const float* __restrict__ qp,
    const float* __restrict__ gamma, const float* __restrict__ beta,
    const float* __restrict__ hw, const float* __restrict__ hb,
    float* __restrict__ out) {
  __shared__ float wsum[8][8];
  __shared__ float stats[8];
  const int tid = threadIdx.x;  // batch index

  const f4* pp = (const f4*)(partials + tid * 16);
  f4 s0 = pp[0], s1 = pp[1], s2 = pp[2], s3 = pp[3];
  float f[4];
  f[0] = (s0.x + s1.x + s2.x + s3.x) * (1.f / 1024.f);
  f[1] = (s0.y + s1.y + s2.y + s3.y) * (1.f / 1024.f);
  f[2] = (s0.z + s1.z + s2.z + s3.z) * (1.f / 1024.f);
  f[3] = (s0.w + s1.w + s2.w + s3.w) * (1.f / 1024.f);

  float a0r[4], a0i[4], a1r[4], a1i[4];
#pragma unroll
  for (int i = 0; i < 4; ++i) {
    float cy, sy, cx, sx;
    __sincosf(0.5f * f[i], &sy, &cy);
    __sincosf(0.5f * uload(qp + i), &sx, &cx);
    a0r[i] = cx * cy; a0i[i] = -sx * sy;
    a1r[i] = cx * sy; a1i[i] = -sx * cy;
  }

  float pr[16], pi[16];
#pragma unroll
  for (int j = 0; j < 16; ++j) {
    float rr = 1.f, ii = 0.f;
#pragma unroll
    for (int w = 0; w < 4; ++w) {
      int bit = (j >> (3 - w)) & 1;
      float ar = bit ? a1r[w] : a0r[w];
      float ai = bit ? a1i[w] : a0i[w];
      float t = rr * ar - ii * ai;
      ii = rr * ai + ii * ar;
      rr = t;
    }
    pr[j] = rr; pi[j] = ii;
  }

  constexpr int comp[16] = {0, 1, 3, 2, 6, 7, 5, 4, 12, 13, 15, 14, 10, 11, 9, 8};
  float qv[4] = {0.f, 0.f, 0.f, 0.f};
#pragma unroll
  for (int j = 0; j < 16; ++j) {
    int s = comp[j];
    float p = pr[s] * pr[s] + pi[s] * pi[s];
#pragma unroll
    for (int i = 0; i < 4; ++i)
      qv[i] += ((j >> (3 - i)) & 1) ? -p : p;
  }

  float v[8];
#pragma unroll
  for (int i = 0; i < 4; ++i) { v[i] = qv[i]; v[4 + i] = qv[i] * qv[i]; }
#pragma unroll
  for (int k = 0; k < 8; ++k)
#pragma unroll
    for (int off = 32; off > 0; off >>= 1) v[k] += __shfl_down(v[k], off);
  const int lane = tid & 63, w = tid >> 6;
  if (lane == 0) {
#pragma unroll
    for (int k = 0; k < 8; ++k) wsum[w][k] = v[k];
  }
  __syncthreads();
  if (tid < 8) {
    float s = 0.f;
#pragma unroll
    for (int ww = 0; ww < 8; ++ww) s += wsum[ww][tid];
    stats[tid] = s * (1.f / 512.f);
  }
  __syncthreads();

  float nm[4];
#pragma unroll
  for (int i = 0; i < 4; ++i) {
    float mu  = stats[i];
    float var = stats[4 + i] - mu * mu;
    nm[i] = uload(gamma + i) * (qv[i] - mu) * rsqrtf(var + EPS) + uload(beta + i);
  }
#pragma unroll
  for (int k = 0; k < 4; ++k) {
    float o = uload(hb + k);
#pragma unroll
    for (int i = 0; i < 4; ++i) o = fmaf(nm[i], uload(hw + k * 4 + i), o);
    out[tid * 4 + k] = o;
  }
}

extern "C" void kernel_launch(void* const* d_in, const int* in_sizes, int n_in,
                              void* d_out, int out_size, void* d_ws, size_t ws_size,
                              hipStream_t stream) {
  const float* x  = (const float*)d_in[0];
  const float* w1 = (const float*)d_in[1];
  const float* b1 = (const float*)d_in[2];
  const float* w2 = (const float*)d_in[3];
  const float* b2 = (const float*)d_in[4];
  const float* qp = (const float*)d_in[5];
  const float* gm = (const float*)d_in[6];
  const float* bt = (const float*)d_in[7];
  const float* hw = (const float*)d_in[8];
  const float* hb = (const float*)d_in[9];
  float* out = (float*)d_out;

  float* partials = (float*)d_ws;  // 512 * 4 strips * 4 oc floats = 32 KB

  k12_fused<<<512 * 4, 256, 0, stream>>>(x, w1, b1, w2, b2, partials);
  k3_tail<<<1, 512, 0, stream>>>(partials, qp, gm, bt, hw, hb, out);
}

// Round 6
// 127.641 us; speedup vs baseline: 1.2166x; 1.2166x over previous
//
#include <hip/hip_runtime.h>

#define EPS 1e-5f

typedef float f2 __attribute__((ext_vector_type(2)));
typedef float f4 __attribute__((ext_vector_type(4)));

// Broadcast a block-uniform load into an SGPR (scalars).
__device__ __forceinline__ float uload(const float* __restrict__ p) {
  return __int_as_float(__builtin_amdgcn_readfirstlane(__float_as_int(*p)));
}

// ---------------------------------------------------------------------------
// K12: fused conv1(1->8)+ReLU+pool + conv2(4 used oc of 16)+ReLU+pool + sum.
// Block = (batch b, quarter q): pooled2 rows 8q..8q+7, 256 threads.
// Hard-won structure notes:
//  - conv1 reads x from GLOBAL (r3). LDS xtile stride-2 reads = 1.06M conflict
//    cycles (r4). Never again.
//  - launch_bounds 2nd arg MUST stay <=4: (256,6) capped VGPRs at ~85 and the
//    compiler spilled everything to scratch -> 95 MB HBM writes, 80 us (r5).
//    (256,4) = 128-VGPR cap is the known spill-free setting.
//  - p1 in two 4-channel passes keeps LDS at 21.5 KB; weights staged in LDS
//    padded to stride 12 -> uniform ds_read_b128 broadcasts.
// ---------------------------------------------------------------------------
__global__ __launch_bounds__(256, 4) void k12_fused(
    const float* __restrict__ x, const float* __restrict__ w1,
    const float* __restrict__ b1, const float* __restrict__ w2,
    const float* __restrict__ b2, float* __restrict__ partials) {
  __shared__ float p1[4][18][66];  // one 4-channel group; col idx = col+1
  __shared__ float w1s[104];       // [oc][12]: k0..8, bias at [oc*12+9]
  __shared__ float w2s[392];       // [(oc*8+ic)][12] (384) + b2[4] at 384..
  __shared__ float wred[4][4];

  const int q   = blockIdx.x & 3;
  const int b   = blockIdx.x >> 2;
  const int tid = threadIdx.x;
  const float* xb = x + (size_t)b * (128 * 128);

  // ---- stage weights, padded 9 -> 12 for aligned b128 broadcast reads ----
  if (tid < 72) w1s[(tid / 9) * 12 + tid % 9] = w1[tid];
  if (tid >= 72 && tid < 80) w1s[(tid - 72) * 12 + 9] = b1[tid - 72];
  {
    int t = tid;                      // first 288 floats of w2 = oc 0..3
    w2s[(t / 9) * 12 + t % 9] = w2[t];
    t = tid + 256;
    if (t < 288) w2s[(t / 9) * 12 + t % 9] = w2[t];
  }
  if (tid < 4) w2s[384 + tid] = b2[tid];
  // zero p1's SAME-padding halo columns (constant across both passes)
  if (tid < 72) {
    int ic = tid / 18, r = tid % 18;
    p1[ic][r][0]  = 0.f;
    p1[ic][r][65] = 0.f;
  }
  __syncthreads();

  const int px2  = tid & 31;
  const int py2l = tid >> 5;  // 0..7

  // conv2 accumulators (bias-init once; accumulate across both passes)
  float acc[4][2][2];
#pragma unroll
  for (int oc = 0; oc < 4; ++oc) {
    float bias = w2s[384 + oc];
    acc[oc][0][0] = bias; acc[oc][0][1] = bias;
    acc[oc][1][0] = bias; acc[oc][1][1] = bias;
  }

#pragma unroll 1
  for (int g = 0; g < 2; ++g) {
    if (g) __syncthreads();  // pass-0 conv2 reads done before p1 overwrite

    // ---- conv1 + ReLU + pool for channels 4g..4g+3 -> p1 ----
    // window = (gl, col pair i): pooled cols 2i,2i+1 share a 4x6 x-window.
#pragma unroll 1
    for (int pos = tid; pos < 576; pos += 256) {
      const int gl = pos >> 5, i = pos & 31;
      const int G  = 16 * q - 1 + gl;
      const bool vG = ((unsigned)G) < 64u;
      const int xr0 = 2 * G - 1;
      float xin[4][6];  // x cols 4i-1 .. 4i+4, rows xr0..xr0+3 (clamped)
#pragma unroll
      for (int r = 0; r < 4; ++r) {
        const int row  = xr0 + r;
        const bool rok = vG && ((unsigned)row < 128u);
        const int rowc = min(max(row, 0), 127);
        const float* rp = xb + rowc * 128;
        const float le = rp[(i == 0) ? 0 : (4 * i - 1)];
        const f4 mid   = *(const f4*)(rp + 4 * i);        // 16B-aligned
        const float ri = rp[(i == 31) ? 127 : (4 * i + 4)];
        xin[r][0] = (rok && i != 0)  ? le    : 0.f;
        xin[r][1] = rok              ? mid.x : 0.f;
        xin[r][2] = rok              ? mid.y : 0.f;
        xin[r][3] = rok              ? mid.z : 0.f;
        xin[r][4] = rok              ? mid.w : 0.f;
        xin[r][5] = (rok && i != 31) ? ri    : 0.f;
      }
#pragma unroll
      for (int oc = 0; oc < 4; ++oc) {
        const int o = 4 * g + oc;
        const f4 wA = *(const f4*)&w1s[o * 12];
        const f4 wB = *(const f4*)&w1s[o * 12 + 4];
        const f2 wC = *(const f2*)&w1s[o * 12 + 8];  // (w8, bias)
        const float wv[9] = {wA.x, wA.y, wA.z, wA.w, wB.x, wB.y, wB.z, wB.w, wC.x};
#pragma unroll
        for (int h = 0; h < 2; ++h) {  // pooled col 2i+h
          float best = 0.f;            // ReLU floor
#pragma unroll
          for (int dy = 0; dy < 2; ++dy)
#pragma unroll
            for (int dx = 0; dx < 2; ++dx) {
              float a = wC.y;
#pragma unroll
              for (int ky = 0; ky < 3; ++ky)
#pragma unroll
                for (int kx = 0; kx < 3; ++kx)
                  a = fmaf(xin[dy + ky][2 * h + dx + kx], wv[ky * 3 + kx], a);
              best = fmaxf(best, a);
            }
          p1[oc][gl][2 * i + 1 + h] = vG ? best : 0.f;
        }
      }
    }
    __syncthreads();

    // ---- conv2 partial: ic 4g..4g+3, all 4 needed oc ----
#pragma unroll 1
    for (int ic = 0; ic < 4; ++ic) {
      float xin[4][4];
#pragma unroll
      for (int r = 0; r < 4; ++r) {
        // even 8B-aligned float2 reads — measured ~0 conflicts in r3
        const f2* rp = (const f2*)&p1[ic][2 * py2l + r][2 * px2];
        f2 v0 = rp[0], v1 = rp[1];
        xin[r][0] = v0.x; xin[r][1] = v0.y; xin[r][2] = v1.x; xin[r][3] = v1.y;
      }
#pragma unroll
      for (int oc = 0; oc < 4; ++oc) {
        const int wi = (oc * 8 + 4 * g + ic) * 12;
        const f4 wA = *(const f4*)&w2s[wi];
        const f4 wB = *(const f4*)&w2s[wi + 4];
        const float w8 = w2s[wi + 8];
        const float wv[9] = {wA.x, wA.y, wA.z, wA.w, wB.x, wB.y, wB.z, wB.w, w8};
#pragma unroll
        for (int dy = 0; dy < 2; ++dy)
#pragma unroll
          for (int dx = 0; dx < 2; ++dx) {
#pragma unroll
            for (int ky = 0; ky < 3; ++ky)
#pragma unroll
              for (int kx = 0; kx < 3; ++kx)
                acc[oc][dy][dx] =
                    fmaf(xin[dy + ky][dx + kx], wv[ky * 3 + kx], acc[oc][dy][dx]);
          }
      }
    }
  }

  // ---- ReLU + 2x2 pool + spatial partial-sum ----
  const int lane = tid & 63, w = tid >> 6;
#pragma unroll
  for (int oc = 0; oc < 4; ++oc) {
    float p = fmaxf(fmaxf(fmaxf(acc[oc][0][0], acc[oc][0][1]),
                          fmaxf(acc[oc][1][0], acc[oc][1][1])), 0.f);
#pragma unroll
    for (int off = 32; off > 0; off >>= 1) p += __shfl_down(p, off);
    if (lane == 0) wred[w][oc] = p;
  }
  __syncthreads();
  if (tid < 4) {
    float s = wred[0][tid] + wred[1][tid] + wred[2][tid] + wred[3][tid];
    partials[((size_t)b * 4 + q) * 4 + tid] = s;
  }
}

// ---------------------------------------------------------------------------
// K3: feats -> quantum circuit -> batchnorm (over batch=512) -> head.
// Single block, 512 threads; thread = batch element. Shuffle reductions.
// ---------------------------------------------------------------------------
__global__ __launch_bounds__(512) void k3_tail(
    const float* __restrict__ partials, const float* __restrict__ qp,
    const float* __restrict__ gamma, const float* __restrict__ beta,
    const float* __restrict__ hw, const float* __restrict__ hb,
    float* __restrict__ out) {
  __shared__ float wsum[8][8];
  __shared__ float stats[8];
  const int tid = threadIdx.x;  // batch index

  const f4* pp = (const f4*)(partials + tid * 16);
  f4 s0 = pp[0], s1 = pp[1], s2 = pp[2], s3 = pp[3];
  float f[4];
  f[0] = (s0.x + s1.x + s2.x + s3.x) * (1.f / 1024.f);
  f[1] = (s0.y + s1.y + s2.y + s3.y) * (1.f / 1024.f);
  f[2] = (s0.z + s1.z + s2.z + s3.z) * (1.f / 1024.f);
  f[3] = (s0.w + s1.w + s2.w + s3.w) * (1.f / 1024.f);

  float a0r[4], a0i[4], a1r[4], a1i[4];
#pragma unroll
  for (int i = 0; i < 4; ++i) {
    float cy, sy, cx, sx;
    __sincosf(0.5f * f[i], &sy, &cy);
    __sincosf(0.5f * uload(qp + i), &sx, &cx);
    a0r[i] = cx * cy; a0i[i] = -sx * sy;
    a1r[i] = cx * sy; a1i[i] = -sx * cy;
  }

  float pr[16], pi[16];
#pragma unroll
  for (int j = 0; j < 16; ++j) {
    float rr = 1.f, ii = 0.f;
#pragma unroll
    for (int w = 0; w < 4; ++w) {
      int bit = (j >> (3 - w)) & 1;
      float ar = bit ? a1r[w] : a0r[w];
      float ai = bit ? a1i[w] : a0i[w];
      float t = rr * ar - ii * ai;
      ii = rr * ai + ii * ar;
      rr = t;
    }
    pr[j] = rr; pi[j] = ii;
  }

  constexpr int comp[16] = {0, 1, 3, 2, 6, 7, 5, 4, 12, 13, 15, 14, 10, 11, 9, 8};
  float qv[4] = {0.f, 0.f, 0.f, 0.f};
#pragma unroll
  for (int j = 0; j < 16; ++j) {
    int s = comp[j];
    float p = pr[s] * pr[s] + pi[s] * pi[s];
#pragma unroll
    for (int i = 0; i < 4; ++i)
      qv[i] += ((j >> (3 - i)) & 1) ? -p : p;
  }

  float v[8];
#pragma unroll
  for (int i = 0; i < 4; ++i) { v[i] = qv[i]; v[4 + i] = qv[i] * qv[i]; }
#pragma unroll
  for (int k = 0; k < 8; ++k)
#pragma unroll
    for (int off = 32; off > 0; off >>= 1) v[k] += __shfl_down(v[k], off);
  const int lane = tid & 63, w = tid >> 6;
  if (lane == 0) {
#pragma unroll
    for (int k = 0; k < 8; ++k) wsum[w][k] = v[k];
  }
  __syncthreads();
  if (tid < 8) {
    float s = 0.f;
#pragma unroll
    for (int ww = 0; ww < 8; ++ww) s += wsum[ww][tid];
    stats[tid] = s * (1.f / 512.f);
  }
  __syncthreads();

  float nm[4];
#pragma unroll
  for (int i = 0; i < 4; ++i) {
    float mu  = stats[i];
    float var = stats[4 + i] - mu * mu;
    nm[i] = uload(gamma + i) * (qv[i] - mu) * rsqrtf(var + EPS) + uload(beta + i);
  }
#pragma unroll
  for (int k = 0; k < 4; ++k) {
    float o = uload(hb + k);
#pragma unroll
    for (int i = 0; i < 4; ++i) o = fmaf(nm[i], uload(hw + k * 4 + i), o);
    out[tid * 4 + k] = o;
  }
}

extern "C" void kernel_launch(void* const* d_in, const int* in_sizes, int n_in,
                              void* d_out, int out_size, void* d_ws, size_t ws_size,
                              hipStream_t stream) {
  const float* x  = (const float*)d_in[0];
  const float* w1 = (const float*)d_in[1];
  const float* b1 = (const float*)d_in[2];
  const float* w2 = (const float*)d_in[3];
  const float* b2 = (const float*)d_in[4];
  const float* qp = (const float*)d_in[5];
  const float* gm = (const float*)d_in[6];
  const float* bt = (const float*)d_in[7];
  const float* hw = (const float*)d_in[8];
  const float* hb = (const float*)d_in[9];
  float* out = (float*)d_out;

  float* partials = (float*)d_ws;  // 512 * 4 strips * 4 oc floats = 32 KB

  k12_fused<<<512 * 4, 256, 0, stream>>>(x, w1, b1, w2, b2, partials);
  k3_tail<<<1, 512, 0, stream>>>(partials, qp, gm, bt, hw, hb, out);
}

// Round 7
// 123.176 us; speedup vs baseline: 1.2606x; 1.0362x over previous
//
#include <hip/hip_runtime.h>

#define EPS 1e-5f

typedef float f2 __attribute__((ext_vector_type(2)));
typedef float f4 __attribute__((ext_vector_type(4)));

// Broadcast a block-uniform load into an SGPR (scalars).
__device__ __forceinline__ float uload(const float* __restrict__ p) {
  return __int_as_float(__builtin_amdgcn_readfirstlane(__float_as_int(*p)));
}

__device__ __forceinline__ f2 fma2(f2 a, f2 b, f2 c) {
  return __builtin_elementwise_fma(a, b, c);
}
__device__ __forceinline__ f2 splat2(float s) { f2 r; r.x = s; r.y = s; return r; }

// ---------------------------------------------------------------------------
// K12: fused conv1(1->8)+ReLU+pool + conv2(4 used oc of 16)+ReLU+pool + sum.
// Block = (batch b, quarter q): pooled2 rows 8q..8q+7, 256 threads.
// Hard-won notes:
//  - conv1 reads x from GLOBAL (r3). LDS xtile stride-2 reads = 1.06M conflict
//    cycles (r4). Never again.
//  - launch_bounds must not starve the allocator: (256,6) -> scratch spill,
//    95 MB HBM writes, 80 us (r5). Keep (256,4); runtime residency is set by
//    actual VGPR/LDS use anyway (r6: 7 blocks/CU possible, time unchanged).
//  - r6 showed instruction count, not occupancy, is binding: VALU busy 66%,
//    only ~half useful fma. This round: pack oc-pairs into float2 and use
//    v_pk_fma_f32 (via __builtin_elementwise_fma) to halve fma instructions.
//    Weights staged TRANSPOSED in LDS so oc-pairs are aligned b64 reads and
//    per-output fp32 summation order is unchanged (bit-exact vs r6).
// ---------------------------------------------------------------------------
__global__ __launch_bounds__(256, 4) void k12_fused(
    const float* __restrict__ x, const float* __restrict__ w1,
    const float* __restrict__ b1, const float* __restrict__ w2,
    const float* __restrict__ b2, float* __restrict__ partials) {
  __shared__ float p1[4][18][66];  // one 4-channel group; col idx = col+1
  __shared__ float w1t[72];        // [k][oc8]  transposed conv1 weights
  __shared__ float b1s[8];
  __shared__ float w2t[288];       // [ic8][k9][oc4] transposed conv2 weights
  __shared__ float b2s[4];
  __shared__ float wred[4][4];

  const int q   = blockIdx.x & 3;
  const int b   = blockIdx.x >> 2;
  const int tid = threadIdx.x;
  const float* xb = x + (size_t)b * (128 * 128);

  // ---- stage weights transposed ----
  if (tid < 72) {
    int oc = tid / 9, k = tid % 9;
    w1t[k * 8 + oc] = w1[tid];
  } else if (tid < 80) {
    b1s[tid - 72] = b1[tid - 72];
  } else if (tid < 84) {
    b2s[tid - 80] = b2[tid - 80];
  }
  {
    int t = tid;  // first 288 floats of w2 = oc 0..3
    {
      int oc = t / 72, rem = t % 72, ic = rem / 9, k = rem % 9;
      w2t[(ic * 9 + k) * 4 + oc] = w2[t];
    }
    t = tid + 256;
    if (t < 288) {
      int oc = t / 72, rem = t % 72, ic = rem / 9, k = rem % 9;
      w2t[(ic * 9 + k) * 4 + oc] = w2[t];
    }
  }
  // zero p1's SAME-padding halo columns (constant across both passes)
  if (tid < 72) {
    int ic = tid / 18, r = tid % 18;
    p1[ic][r][0]  = 0.f;
    p1[ic][r][65] = 0.f;
  }
  __syncthreads();

  const int px2  = tid & 31;
  const int py2l = tid >> 5;  // 0..7

  // conv2 accumulators: [ocpair p][dy][dx], f2 = {oc 2p, oc 2p+1}
  f2 acc[2][2][2];
#pragma unroll
  for (int p = 0; p < 2; ++p) {
    const f2 bias = *(const f2*)&b2s[2 * p];
    acc[p][0][0] = bias; acc[p][0][1] = bias;
    acc[p][1][0] = bias; acc[p][1][1] = bias;
  }

#pragma unroll 1
  for (int g = 0; g < 2; ++g) {
    if (g) __syncthreads();  // pass-0 conv2 reads done before p1 overwrite

    // conv1 weight oc-pairs for this group -> registers (uniform b64 reads)
    f2 wp[9][2], bias1[2];
#pragma unroll
    for (int k = 0; k < 9; ++k) {
      wp[k][0] = *(const f2*)&w1t[k * 8 + 4 * g];
      wp[k][1] = *(const f2*)&w1t[k * 8 + 4 * g + 2];
    }
    bias1[0] = *(const f2*)&b1s[4 * g];
    bias1[1] = *(const f2*)&b1s[4 * g + 2];

    // ---- conv1 + ReLU + pool for channels 4g..4g+3 -> p1 ----
    // window = (gl, col pair i): pooled cols 2i,2i+1 share a 4x6 x-window.
#pragma unroll 1
    for (int pos = tid; pos < 576; pos += 256) {
      const int gl = pos >> 5, i = pos & 31;
      const int G  = 16 * q - 1 + gl;
      const bool vG = ((unsigned)G) < 64u;
      const int xr0 = 2 * G - 1;
      float xin[4][6];  // x cols 4i-1 .. 4i+4, rows xr0..xr0+3 (clamped)
#pragma unroll
      for (int r = 0; r < 4; ++r) {
        const int row  = xr0 + r;
        const bool rok = vG && ((unsigned)row < 128u);
        const int rowc = min(max(row, 0), 127);
        const float* rp = xb + rowc * 128;
        const float le = rp[(i == 0) ? 0 : (4 * i - 1)];
        const f4 mid   = *(const f4*)(rp + 4 * i);        // 16B-aligned
        const float ri = rp[(i == 31) ? 127 : (4 * i + 4)];
        xin[r][0] = (rok && i != 0)  ? le    : 0.f;
        xin[r][1] = rok              ? mid.x : 0.f;
        xin[r][2] = rok              ? mid.y : 0.f;
        xin[r][3] = rok              ? mid.z : 0.f;
        xin[r][4] = rok              ? mid.w : 0.f;
        xin[r][5] = (rok && i != 31) ? ri    : 0.f;
      }
      f2 best[2][2];  // [ocpair p][h]
#pragma unroll
      for (int p = 0; p < 2; ++p)
#pragma unroll
        for (int h = 0; h < 2; ++h) best[p][h] = splat2(0.f);  // ReLU floor
#pragma unroll
      for (int dy = 0; dy < 2; ++dy)
#pragma unroll
        for (int dx = 0; dx < 2; ++dx) {
#pragma unroll
          for (int p = 0; p < 2; ++p)
#pragma unroll
            for (int h = 0; h < 2; ++h) {
              f2 a = bias1[p];
#pragma unroll
              for (int ky = 0; ky < 3; ++ky)
#pragma unroll
                for (int kx = 0; kx < 3; ++kx)
                  a = fma2(wp[ky * 3 + kx][p],
                           splat2(xin[dy + ky][2 * h + dx + kx]), a);
              best[p][h].x = fmaxf(best[p][h].x, a.x);
              best[p][h].y = fmaxf(best[p][h].y, a.y);
            }
        }
#pragma unroll
      for (int p = 0; p < 2; ++p)
#pragma unroll
        for (int h = 0; h < 2; ++h) {
          p1[2 * p][gl][2 * i + 1 + h]     = vG ? best[p][h].x : 0.f;
          p1[2 * p + 1][gl][2 * i + 1 + h] = vG ? best[p][h].y : 0.f;
        }
    }
    __syncthreads();

    // ---- conv2 partial: ic 4g..4g+3, all 4 needed oc (oc-pair packed) ----
#pragma unroll 1
    for (int ic = 0; ic < 4; ++ic) {
      float xin[4][4];
#pragma unroll
      for (int r = 0; r < 4; ++r) {
        // even 8B-aligned float2 reads — measured near-0 conflicts in r3
        const f2* rp = (const f2*)&p1[ic][2 * py2l + r][2 * px2];
        f2 v0 = rp[0], v1 = rp[1];
        xin[r][0] = v0.x; xin[r][1] = v0.y; xin[r][2] = v1.x; xin[r][3] = v1.y;
      }
      const int icg = 4 * g + ic;
#pragma unroll
      for (int ky = 0; ky < 3; ++ky)
#pragma unroll
        for (int kx = 0; kx < 3; ++kx) {
          const int k = ky * 3 + kx;
          const f2 w0 = *(const f2*)&w2t[(icg * 9 + k) * 4];
          const f2 w1p = *(const f2*)&w2t[(icg * 9 + k) * 4 + 2];
#pragma unroll
          for (int dy = 0; dy < 2; ++dy)
#pragma unroll
            for (int dx = 0; dx < 2; ++dx) {
              const f2 xs = splat2(xin[dy + ky][dx + kx]);
              acc[0][dy][dx] = fma2(w0, xs, acc[0][dy][dx]);
              acc[1][dy][dx] = fma2(w1p, xs, acc[1][dy][dx]);
            }
        }
    }
  }

  // ---- ReLU + 2x2 pool + spatial partial-sum ----
  const int lane = tid & 63, w = tid >> 6;
#pragma unroll
  for (int p = 0; p < 2; ++p) {
    f2 m01;
    m01.x = fmaxf(fmaxf(fmaxf(acc[p][0][0].x, acc[p][0][1].x),
                        fmaxf(acc[p][1][0].x, acc[p][1][1].x)), 0.f);
    m01.y = fmaxf(fmaxf(fmaxf(acc[p][0][0].y, acc[p][0][1].y),
                        fmaxf(acc[p][1][0].y, acc[p][1][1].y)), 0.f);
#pragma unroll
    for (int off = 32; off > 0; off >>= 1) {
      m01.x += __shfl_down(m01.x, off);
      m01.y += __shfl_down(m01.y, off);
    }
    if (lane == 0) { wred[w][2 * p] = m01.x; wred[w][2 * p + 1] = m01.y; }
  }
  __syncthreads();
  if (tid < 4) {
    float s = wred[0][tid] + wred[1][tid] + wred[2][tid] + wred[3][tid];
    partials[((size_t)b * 4 + q) * 4 + tid] = s;
  }
}

// ---------------------------------------------------------------------------
// K3: feats -> quantum circuit -> batchnorm (over batch=512) -> head.
// Single block, 512 threads; thread = batch element. Shuffle reductions.
// ---------------------------------------------------------------------------
__global__ __launch_bounds__(512) void k3_tail(
    const float* __restrict__ partials, const float* __restrict__ qp,
    const float* __restrict__ gamma, const float* __restrict__ beta,
    const float* __restrict__ hw, const float* __restrict__ hb,
    float* __restrict__ out) {
  __shared__ float wsum[8][8];
  __shared__ float stats[8];
  const int tid = threadIdx.x;  // batch index

  const f4* pp = (const f4*)(partials + tid * 16);
  f4 s0 = pp[0], s1 = pp[1], s2 = pp[2], s3 = pp[3];
  float f[4];
  f[0] = (s0.x + s1.x + s2.x + s3.x) * (1.f / 1024.f);
  f[1] = (s0.y + s1.y + s2.y + s3.y) * (1.f / 1024.f);
  f[2] = (s0.z + s1.z + s2.z + s3.z) * (1.f / 1024.f);
  f[3] = (s0.w + s1.w + s2.w + s3.w) * (1.f / 1024.f);

  float a0r[4], a0i[4], a1r[4], a1i[4];
#pragma unroll
  for (int i = 0; i < 4; ++i) {
    float cy, sy, cx, sx;
    __sincosf(0.5f * f[i], &sy, &cy);
    __sincosf(0.5f * uload(qp + i), &sx, &cx);
    a0r[i] = cx * cy; a0i[i] = -sx * sy;
    a1r[i] = cx * sy; a1i[i] = -sx * cy;
  }

  float pr[16], pi[16];
#pragma unroll
  for (int j = 0; j < 16; ++j) {
    float rr = 1.f, ii = 0.f;
#pragma unroll
    for (int w = 0; w < 4; ++w) {
      int bit = (j >> (3 - w)) & 1;
      float ar = bit ? a1r[w] : a0r[w];
      float ai = bit ? a1i[w] : a0i[w];
      float t = rr * ar - ii * ai;
      ii = rr * ai + ii * ar;
      rr = t;
    }
    pr[j] = rr; pi[j] = ii;
  }

  constexpr int comp[16] = {0, 1, 3, 2, 6, 7, 5, 4, 12, 13, 15, 14, 10, 11, 9, 8};
  float qv[4] = {0.f, 0.f, 0.f, 0.f};
#pragma unroll
  for (int j = 0; j < 16; ++j) {
    int s = comp[j];
    float p = pr[s] * pr[s] + pi[s] * pi[s];
#pragma unroll
    for (int i = 0; i < 4; ++i)
      qv[i] += ((j >> (3 - i)) & 1) ? -p : p;
  }

  float v[8];
#pragma unroll
  for (int i = 0; i < 4; ++i) { v[i] = qv[i]; v[4 + i] = qv[i] * qv[i]; }
#pragma unroll
  for (int k = 0; k < 8; ++k)
#pragma unroll
    for (int off = 32; off > 0; off >>= 1) v[k] += __shfl_down(v[k], off);
  const int lane = tid & 63, w = tid >> 6;
  if (lane == 0) {
#pragma unroll
    for (int k = 0; k < 8; ++k) wsum[w][k] = v[k];
  }
  __syncthreads();
  if (tid < 8) {
    float s = 0.f;
#pragma unroll
    for (int ww = 0; ww < 8; ++ww) s += wsum[ww][tid];
    stats[tid] = s * (1.f / 512.f);
  }
  __syncthreads();

  float nm[4];
#pragma unroll
  for (int i = 0; i < 4; ++i) {
    float mu  = stats[i];
    float var = stats[4 + i] - mu * mu;
    nm[i] = uload(gamma + i) * (qv[i] - mu) * rsqrtf(var + EPS) + uload(beta + i);
  }
#pragma unroll
  for (int k = 0; k < 4; ++k) {
    float o = uload(hb + k);
#pragma unroll
    for (int i = 0; i < 4; ++i) o = fmaf(nm[i], uload(hw + k * 4 + i), o);
    out[tid * 4 + k] = o;
  }
}

extern "C" void kernel_launch(void* const* d_in, const int* in_sizes, int n_in,
                              void* d_out, int out_size, void* d_ws, size_t ws_size,
                              hipStream_t stream) {
  const float* x  = (const float*)d_in[0];
  const float* w1 = (const float*)d_in[1];
  const float* b1 = (const float*)d_in[2];
  const float* w2 = (const float*)d_in[3];
  const float* b2 = (const float*)d_in[4];
  const float* qp = (const float*)d_in[5];
  const float* gm = (const float*)d_in[6];
  const float* bt = (const float*)d_in[7];
  const float* hw = (const float*)d_in[8];
  const float* hb = (const float*)d_in[9];
  float* out = (float*)d_out;

  float* partials = (float*)d_ws;  // 512 * 4 strips * 4 oc floats = 32 KB

  k12_fused<<<512 * 4, 256, 0, stream>>>(x, w1, b1, w2, b2, partials);
  k3_tail<<<1, 512, 0, stream>>>(partials, qp, gm, bt, hw, hb, out);
}

// Round 8
// 121.032 us; speedup vs baseline: 1.2830x; 1.0177x over previous
//
#include <hip/hip_runtime.h>

#define EPS 1e-5f

typedef float f2 __attribute__((ext_vector_type(2)));
typedef float f4 __attribute__((ext_vector_type(4)));

// Broadcast a block-uniform load into an SGPR (scalars).
__device__ __forceinline__ float uload(const float* __restrict__ p) {
  return __int_as_float(__builtin_amdgcn_readfirstlane(__float_as_int(*p)));
}

__device__ __forceinline__ f2 fma2(f2 a, f2 b, f2 c) {
  return __builtin_elementwise_fma(a, b, c);
}
__device__ __forceinline__ f2 splat2(float s) { f2 r; r.x = s; r.y = s; return r; }

// ---------------------------------------------------------------------------
// K12: fused conv1(1->8)+ReLU+pool + conv2(4 used oc of 16)+ReLU+pool + sum.
// Block = (batch b, quarter q): pooled2 rows 8q..8q+7, 256 threads.
// Hard-won notes (r1-r7):
//  - conv1 reads x from GLOBAL. LDS xtile stride-2 reads = 1.06M conflict
//    cycles (r4). Never again.
//  - launch_bounds (256,6) -> scratch spill, 95 MB HBM writes, 80 us (r5).
//    Keep (256,4); extra occupancy beyond 4 blocks/CU is worthless anyway
//    (r6: 21.5 KB LDS, 7 blocks/CU possible, identical time to 4).
//  - pk_fma (oc-pairs in f2) halved VALU-busy as predicted (r7: 33->22.5 us);
//    kernel is now LATENCY-bound (VALUBusy 49%).
//  - This round: SINGLE conv1 pass — load each x window once (6912 global
//    loads/block vs 13824), compute all 8 oc (weight halves sequentially from
//    LDS to cap live VGPRs), full 8-ch p1 (39.6 KB LDS, still 4 blocks/CU),
//    barriers 4 -> 2.
// ---------------------------------------------------------------------------
__global__ __launch_bounds__(256, 4) void k12_fused(
    const float* __restrict__ x, const float* __restrict__ w1,
    const float* __restrict__ b1, const float* __restrict__ w2,
    const float* __restrict__ b2, float* __restrict__ partials) {
  __shared__ float p1[8][18][66];  // pooled1 tile; col idx = col+1 (halo)
  __shared__ float w1t[80];        // [k][oc8] transposed (72) + b1[8] at 72..
  __shared__ float w2t[292];       // [ic8][k9][oc4] transposed + b2[4] at 288..
  __shared__ float wred[4][4];

  const int q   = blockIdx.x & 3;
  const int b   = blockIdx.x >> 2;
  const int tid = threadIdx.x;
  const float* xb = x + (size_t)b * (128 * 128);

  // ---- stage weights transposed ----
  if (tid < 72) {
    int oc = tid / 9, k = tid % 9;
    w1t[k * 8 + oc] = w1[tid];
  } else if (tid < 80) {
    w1t[tid] = b1[tid - 72];
  }
  {
    int t = tid;  // first 288 floats of w2 = oc 0..3
    {
      int oc = t / 72, rem = t % 72, ic = rem / 9, k = rem % 9;
      w2t[(ic * 9 + k) * 4 + oc] = w2[t];
    }
    t = tid + 256;
    if (t < 288) {
      int oc = t / 72, rem = t % 72, ic = rem / 9, k = rem % 9;
      w2t[(ic * 9 + k) * 4 + oc] = w2[t];
    }
  }
  if (tid >= 80 && tid < 84) w2t[288 + tid - 80] = b2[tid - 80];
  // zero p1's SAME-padding halo columns (8 channels x 18 rows)
  if (tid >= 96 && tid < 240) {
    int t = tid - 96;
    int ic = t / 18, r = t % 18;
    p1[ic][r][0]  = 0.f;
    p1[ic][r][65] = 0.f;
  }
  __syncthreads();

  // ---- conv1 + ReLU + pool, ALL 8 channels, x window loaded ONCE ----
  // task = (gl, col-pair i): pooled cols 2i,2i+1 share a 4x6 x-window.
#pragma unroll 1
  for (int pos = tid; pos < 576; pos += 256) {
    const int gl = pos >> 5, i = pos & 31;
    const int G  = 16 * q - 1 + gl;
    const bool vG = ((unsigned)G) < 64u;
    const int xr0 = 2 * G - 1;
    float xin[4][6];  // x cols 4i-1 .. 4i+4, rows xr0..xr0+3 (masked)
#pragma unroll
    for (int r = 0; r < 4; ++r) {
      const int row  = xr0 + r;
      const bool rok = vG && ((unsigned)row < 128u);
      const int rowc = min(max(row, 0), 127);
      const float* rp = xb + rowc * 128;
      const float le = rp[(i == 0) ? 0 : (4 * i - 1)];
      const f4 mid   = *(const f4*)(rp + 4 * i);        // 16B-aligned
      const float ri = rp[(i == 31) ? 127 : (4 * i + 4)];
      xin[r][0] = (rok && i != 0)  ? le    : 0.f;
      xin[r][1] = rok              ? mid.x : 0.f;
      xin[r][2] = rok              ? mid.y : 0.f;
      xin[r][3] = rok              ? mid.z : 0.f;
      xin[r][4] = rok              ? mid.w : 0.f;
      xin[r][5] = (rok && i != 31) ? ri    : 0.f;
    }
    // Two sequential oc-halves so only 18+2 weight f2s are live at a time.
#pragma unroll 1
    for (int g = 0; g < 2; ++g) {
      f2 wpx[9][2], bias1[2];
#pragma unroll
      for (int k = 0; k < 9; ++k) {
        wpx[k][0] = *(const f2*)&w1t[k * 8 + 4 * g];
        wpx[k][1] = *(const f2*)&w1t[k * 8 + 4 * g + 2];
      }
      bias1[0] = *(const f2*)&w1t[72 + 4 * g];
      bias1[1] = *(const f2*)&w1t[72 + 4 * g + 2];
#pragma unroll
      for (int p = 0; p < 2; ++p)
#pragma unroll
        for (int h = 0; h < 2; ++h) {  // pooled col 2i+h
          f2 best = splat2(0.f);       // ReLU floor
#pragma unroll
          for (int dy = 0; dy < 2; ++dy)
#pragma unroll
            for (int dx = 0; dx < 2; ++dx) {
              f2 a = bias1[p];
#pragma unroll
              for (int ky = 0; ky < 3; ++ky)
#pragma unroll
                for (int kx = 0; kx < 3; ++kx)
                  a = fma2(wpx[ky * 3 + kx][p],
                           splat2(xin[dy + ky][2 * h + dx + kx]), a);
              best.x = fmaxf(best.x, a.x);
              best.y = fmaxf(best.y, a.y);
            }
          const int oc0 = 4 * g + 2 * p;
          p1[oc0][gl][2 * i + 1 + h]     = vG ? best.x : 0.f;
          p1[oc0 + 1][gl][2 * i + 1 + h] = vG ? best.y : 0.f;
        }
    }
  }
  __syncthreads();

  // ---- conv2 (oc 0..3 packed as 2 f2 pairs) + ReLU + pool + sum ----
  const int px2  = tid & 31;
  const int py2l = tid >> 5;  // 0..7

  f2 acc[2][2][2];  // [ocpair p][dy][dx]
#pragma unroll
  for (int p = 0; p < 2; ++p) {
    const f2 bias = *(const f2*)&w2t[288 + 2 * p];
    acc[p][0][0] = bias; acc[p][0][1] = bias;
    acc[p][1][0] = bias; acc[p][1][1] = bias;
  }

#pragma unroll 1
  for (int ic = 0; ic < 8; ++ic) {
    float xin[4][4];
#pragma unroll
    for (int r = 0; r < 4; ++r) {
      // even 8B-aligned float2 reads — near-0 conflicts (r3)
      const f2* rp = (const f2*)&p1[ic][2 * py2l + r][2 * px2];
      f2 v0 = rp[0], v1 = rp[1];
      xin[r][0] = v0.x; xin[r][1] = v0.y; xin[r][2] = v1.x; xin[r][3] = v1.y;
    }
#pragma unroll
    for (int ky = 0; ky < 3; ++ky)
#pragma unroll
      for (int kx = 0; kx < 3; ++kx) {
        const int k = ky * 3 + kx;
        const f2 w0  = *(const f2*)&w2t[(ic * 9 + k) * 4];
        const f2 w1p = *(const f2*)&w2t[(ic * 9 + k) * 4 + 2];
#pragma unroll
        for (int dy = 0; dy < 2; ++dy)
#pragma unroll
          for (int dx = 0; dx < 2; ++dx) {
            const f2 xs = splat2(xin[dy + ky][dx + kx]);
            acc[0][dy][dx] = fma2(w0, xs, acc[0][dy][dx]);
            acc[1][dy][dx] = fma2(w1p, xs, acc[1][dy][dx]);
          }
      }
  }

  // ---- ReLU + 2x2 pool + spatial partial-sum ----
  const int lane = tid & 63, w = tid >> 6;
#pragma unroll
  for (int p = 0; p < 2; ++p) {
    f2 m01;
    m01.x = fmaxf(fmaxf(fmaxf(acc[p][0][0].x, acc[p][0][1].x),
                        fmaxf(acc[p][1][0].x, acc[p][1][1].x)), 0.f);
    m01.y = fmaxf(fmaxf(fmaxf(acc[p][0][0].y, acc[p][0][1].y),
                        fmaxf(acc[p][1][0].y, acc[p][1][1].y)), 0.f);
#pragma unroll
    for (int off = 32; off > 0; off >>= 1) {
      m01.x += __shfl_down(m01.x, off);
      m01.y += __shfl_down(m01.y, off);
    }
    if (lane == 0) { wred[w][2 * p] = m01.x; wred[w][2 * p + 1] = m01.y; }
  }
  __syncthreads();
  if (tid < 4) {
    float s = wred[0][tid] + wred[1][tid] + wred[2][tid] + wred[3][tid];
    partials[((size_t)b * 4 + q) * 4 + tid] = s;
  }
}

// ---------------------------------------------------------------------------
// K3: feats -> quantum circuit -> batchnorm (over batch=512) -> head.
// Single block, 512 threads; thread = batch element. Shuffle reductions.
// ---------------------------------------------------------------------------
__global__ __launch_bounds__(512) void k3_tail(
    const float* __restrict__ partials, const float* __restrict__ qp,
    const float* __restrict__ gamma, const float* __restrict__ beta,
    const float* __restrict__ hw, const float* __restrict__ hb,
    float* __restrict__ out) {
  __shared__ float wsum[8][8];
  __shared__ float stats[8];
  const int tid = threadIdx.x;  // batch index

  const f4* pp = (const f4*)(partials + tid * 16);
  f4 s0 = pp[0], s1 = pp[1], s2 = pp[2], s3 = pp[3];
  float f[4];
  f[0] = (s0.x + s1.x + s2.x + s3.x) * (1.f / 1024.f);
  f[1] = (s0.y + s1.y + s2.y + s3.y) * (1.f / 1024.f);
  f[2] = (s0.z + s1.z + s2.z + s3.z) * (1.f / 1024.f);
  f[3] = (s0.w + s1.w + s2.w + s3.w) * (1.f / 1024.f);

  float a0r[4], a0i[4], a1r[4], a1i[4];
#pragma unroll
  for (int i = 0; i < 4; ++i) {
    float cy, sy, cx, sx;
    __sincosf(0.5f * f[i], &sy, &cy);
    __sincosf(0.5f * uload(qp + i), &sx, &cx);
    a0r[i] = cx * cy; a0i[i] = -sx * sy;
    a1r[i] = cx * sy; a1i[i] = -sx * cy;
  }

  float pr[16], pi[16];
#pragma unroll
  for (int j = 0; j < 16; ++j) {
    float rr = 1.f, ii = 0.f;
#pragma unroll
    for (int w = 0; w < 4; ++w) {
      int bit = (j >> (3 - w)) & 1;
      float ar = bit ? a1r[w] : a0r[w];
      float ai = bit ? a1i[w] : a0i[w];
      float t = rr * ar - ii * ai;
      ii = rr * ai + ii * ar;
      rr = t;
    }
    pr[j] = rr; pi[j] = ii;
  }

  constexpr int comp[16] = {0, 1, 3, 2, 6, 7, 5, 4, 12, 13, 15, 14, 10, 11, 9, 8};
  float qv[4] = {0.f, 0.f, 0.f, 0.f};
#pragma unroll
  for (int j = 0; j < 16; ++j) {
    int s = comp[j];
    float p = pr[s] * pr[s] + pi[s] * pi[s];
#pragma unroll
    for (int i = 0; i < 4; ++i)
      qv[i] += ((j >> (3 - i)) & 1) ? -p : p;
  }

  float v[8];
#pragma unroll
  for (int i = 0; i < 4; ++i) { v[i] = qv[i]; v[4 + i] = qv[i] * qv[i]; }
#pragma unroll
  for (int k = 0; k < 8; ++k)
#pragma unroll
    for (int off = 32; off > 0; off >>= 1) v[k] += __shfl_down(v[k], off);
  const int lane = tid & 63, w = tid >> 6;
  if (lane == 0) {
#pragma unroll
    for (int k = 0; k < 8; ++k) wsum[w][k] = v[k];
  }
  __syncthreads();
  if (tid < 8) {
    float s = 0.f;
#pragma unroll
    for (int ww = 0; ww < 8; ++ww) s += wsum[ww][tid];
    stats[tid] = s * (1.f / 512.f);
  }
  __syncthreads();

  float nm[4];
#pragma unroll
  for (int i = 0; i < 4; ++i) {
    float mu  = stats[i];
    float var = stats[4 + i] - mu * mu;
    nm[i] = uload(gamma + i) * (qv[i] - mu) * rsqrtf(var + EPS) + uload(beta + i);
  }
#pragma unroll
  for (int k = 0; k < 4; ++k) {
    float o = uload(hb + k);
#pragma unroll
    for (int i = 0; i < 4; ++i) o = fmaf(nm[i], uload(hw + k * 4 + i), o);
    out[tid * 4 + k] = o;
  }
}

extern "C" void kernel_launch(void* const* d_in, const int* in_sizes, int n_in,
                              void* d_out, int out_size, void* d_ws, size_t ws_size,
                              hipStream_t stream) {
  const float* x  = (const float*)d_in[0];
  const float* w1 = (const float*)d_in[1];
  const float* b1 = (const float*)d_in[2];
  const float* w2 = (const float*)d_in[3];
  const float* b2 = (const float*)d_in[4];
  const float* qp = (const float*)d_in[5];
  const float* gm = (const float*)d_in[6];
  const float* bt = (const float*)d_in[7];
  const float* hw = (const float*)d_in[8];
  const float* hb = (const float*)d_in[9];
  float* out = (float*)d_out;

  float* partials = (float*)d_ws;  // 512 * 4 strips * 4 oc floats = 32 KB

  k12_fused<<<512 * 4, 256, 0, stream>>>(x, w1, b1, w2, b2, partials);
  k3_tail<<<1, 512, 0, stream>>>(partials, qp, gm, bt, hw, hb, out);
}

// Round 9
// 120.524 us; speedup vs baseline: 1.2884x; 1.0042x over previous
//
#include <hip/hip_runtime.h>

#define EPS 1e-5f

typedef float f2 __attribute__((ext_vector_type(2)));
typedef float f4 __attribute__((ext_vector_type(4)));

// Broadcast a block-uniform load into an SGPR (scalars).
__device__ __forceinline__ float uload(const float* __restrict__ p) {
  return __int_as_float(__builtin_amdgcn_readfirstlane(__float_as_int(*p)));
}

__device__ __forceinline__ f2 fma2(f2 a, f2 b, f2 c) {
  return __builtin_elementwise_fma(a, b, c);
}
__device__ __forceinline__ f2 splat2(float s) { f2 r; r.x = s; r.y = s; return r; }

// ---------------------------------------------------------------------------
// K12: fused conv1(1->8)+ReLU+pool + conv2(4 used oc of 16)+ReLU+pool + sum.
// Block = (batch b, quarter q): pooled2 rows 8q..8q+7, 256 threads.
// Hard-won notes (r1-r8):
//  - conv1 reads x from GLOBAL. LDS xtile stride-2 reads = 1.06M conflict
//    cycles (r4). Never again.
//  - launch_bounds (256,6) -> scratch spill, 95 MB HBM writes (r5). Keep
//    (256,4); occupancy >4 blocks/CU buys nothing (r6).
//  - pk_fma halved VALU-busy to ~22 us (r7, prediction matched); kernel is
//    latency-bound after that.
//  - r8 profile: harness fill of d_ws (268 MB @ 6.1 TB/s = 43.5 us) dominates
//    the timed loop — the ~60 us residual is uncontrollable. Only k12 is left.
//  - This round: software-pipeline conv1 — each thread batches loads for its
//    2 guaranteed tasks up front, 3rd-task loads issued before task-2 compute;
//    conv2 ic-loop unroll x2 so ds_reads overlap fma. Math order per output
//    unchanged (bit-identical to r7/r8).
// ---------------------------------------------------------------------------
__global__ __launch_bounds__(256, 4) void k12_fused(
    const float* __restrict__ x, const float* __restrict__ w1,
    const float* __restrict__ b1, const float* __restrict__ w2,
    const float* __restrict__ b2, float* __restrict__ partials) {
  __shared__ float p1[8][18][66];  // pooled1 tile; col idx = col+1 (halo)
  __shared__ float w1t[80];        // [k][oc8] transposed (72) + b1[8] at 72..
  __shared__ float w2t[292];       // [ic8][k9][oc4] transposed + b2[4] at 288..
  __shared__ float wred[4][4];

  const int q   = blockIdx.x & 3;
  const int b   = blockIdx.x >> 2;
  const int tid = threadIdx.x;
  const float* xb = x + (size_t)b * (128 * 128);

  // ---- stage weights transposed ----
  if (tid < 72) {
    int oc = tid / 9, k = tid % 9;
    w1t[k * 8 + oc] = w1[tid];
  } else if (tid < 80) {
    w1t[tid] = b1[tid - 72];
  }
  {
    int t = tid;  // first 288 floats of w2 = oc 0..3
    {
      int oc = t / 72, rem = t % 72, ic = rem / 9, k = rem % 9;
      w2t[(ic * 9 + k) * 4 + oc] = w2[t];
    }
    t = tid + 256;
    if (t < 288) {
      int oc = t / 72, rem = t % 72, ic = rem / 9, k = rem % 9;
      w2t[(ic * 9 + k) * 4 + oc] = w2[t];
    }
  }
  if (tid >= 80 && tid < 84) w2t[288 + tid - 80] = b2[tid - 80];
  // zero p1's SAME-padding halo columns (8 channels x 18 rows)
  if (tid >= 96 && tid < 240) {
    int t = tid - 96;
    int ic = t / 18, r = t % 18;
    p1[ic][r][0]  = 0.f;
    p1[ic][r][65] = 0.f;
  }
  __syncthreads();

  // ---- conv1 + ReLU + pool: 576 tasks = (gl 0..17, col-pair i 0..31) ----
  // Every thread owns tasks {tid, tid+256}; tid<64 also owns tid+512.
  // Loads for both guaranteed tasks are issued BEFORE any compute (pipeline).
  auto c1_load = [&](int pos, float xin[4][6]) {
    const int gl = pos >> 5, i = pos & 31;
    const int G  = 16 * q - 1 + gl;
    const bool vG = ((unsigned)G) < 64u;
    const int xr0 = 2 * G - 1;
#pragma unroll
    for (int r = 0; r < 4; ++r) {
      const int row  = xr0 + r;
      const bool rok = vG && ((unsigned)row < 128u);
      const int rowc = min(max(row, 0), 127);
      const float* rp = xb + rowc * 128;
      const float le = rp[(i == 0) ? 0 : (4 * i - 1)];
      const f4 mid   = *(const f4*)(rp + 4 * i);        // 16B-aligned
      const float ri = rp[(i == 31) ? 127 : (4 * i + 4)];
      xin[r][0] = (rok && i != 0)  ? le    : 0.f;
      xin[r][1] = rok              ? mid.x : 0.f;
      xin[r][2] = rok              ? mid.y : 0.f;
      xin[r][3] = rok              ? mid.z : 0.f;
      xin[r][4] = rok              ? mid.w : 0.f;
      xin[r][5] = (rok && i != 31) ? ri    : 0.f;
    }
  };
  auto c1_compute = [&](int pos, const float xin[4][6]) {
    const int gl = pos >> 5, i = pos & 31;
    const int G  = 16 * q - 1 + gl;
    const bool vG = ((unsigned)G) < 64u;
    // Two sequential oc-halves so only 18+2 weight f2s are live at a time.
#pragma unroll 1
    for (int g = 0; g < 2; ++g) {
      f2 wpx[9][2], bias1[2];
#pragma unroll
      for (int k = 0; k < 9; ++k) {
        wpx[k][0] = *(const f2*)&w1t[k * 8 + 4 * g];
        wpx[k][1] = *(const f2*)&w1t[k * 8 + 4 * g + 2];
      }
      bias1[0] = *(const f2*)&w1t[72 + 4 * g];
      bias1[1] = *(const f2*)&w1t[72 + 4 * g + 2];
#pragma unroll
      for (int p = 0; p < 2; ++p)
#pragma unroll
        for (int h = 0; h < 2; ++h) {  // pooled col 2i+h
          f2 best = splat2(0.f);       // ReLU floor
#pragma unroll
          for (int dy = 0; dy < 2; ++dy)
#pragma unroll
            for (int dx = 0; dx < 2; ++dx) {
              f2 a = bias1[p];
#pragma unroll
              for (int ky = 0; ky < 3; ++ky)
#pragma unroll
                for (int kx = 0; kx < 3; ++kx)
                  a = fma2(wpx[ky * 3 + kx][p],
                           splat2(xin[dy + ky][2 * h + dx + kx]), a);
              best.x = fmaxf(best.x, a.x);
              best.y = fmaxf(best.y, a.y);
            }
          const int oc0 = 4 * g + 2 * p;
          p1[oc0][gl][2 * i + 1 + h]     = vG ? best.x : 0.f;
          p1[oc0 + 1][gl][2 * i + 1 + h] = vG ? best.y : 0.f;
        }
    }
  };

  {
    float xin0[4][6], xin1[4][6];
    c1_load(tid, xin0);         // task 0 loads in flight
    c1_load(tid + 256, xin1);   // task 1 loads in flight
    c1_compute(tid, xin0);      // overlaps task-1 load latency
    if (tid < 64) {
      float xin2[4][6];
      c1_load(tid + 512, xin2); // task 2 loads in flight
      c1_compute(tid + 256, xin1);
      c1_compute(tid + 512, xin2);
    } else {
      c1_compute(tid + 256, xin1);
    }
  }
  __syncthreads();

  // ---- conv2 (oc 0..3 packed as 2 f2 pairs) + ReLU + pool + sum ----
  const int px2  = tid & 31;
  const int py2l = tid >> 5;  // 0..7

  f2 acc[2][2][2];  // [ocpair p][dy][dx]
#pragma unroll
  for (int p = 0; p < 2; ++p) {
    const f2 bias = *(const f2*)&w2t[288 + 2 * p];
    acc[p][0][0] = bias; acc[p][0][1] = bias;
    acc[p][1][0] = bias; acc[p][1][1] = bias;
  }

#pragma unroll 2
  for (int ic = 0; ic < 8; ++ic) {
    float xin[4][4];
#pragma unroll
    for (int r = 0; r < 4; ++r) {
      // even 8B-aligned float2 reads — near-0 conflicts (r3)
      const f2* rp = (const f2*)&p1[ic][2 * py2l + r][2 * px2];
      f2 v0 = rp[0], v1 = rp[1];
      xin[r][0] = v0.x; xin[r][1] = v0.y; xin[r][2] = v1.x; xin[r][3] = v1.y;
    }
#pragma unroll
    for (int ky = 0; ky < 3; ++ky)
#pragma unroll
      for (int kx = 0; kx < 3; ++kx) {
        const int k = ky * 3 + kx;
        const f2 w0  = *(const f2*)&w2t[(ic * 9 + k) * 4];
        const f2 w1p = *(const f2*)&w2t[(ic * 9 + k) * 4 + 2];
#pragma unroll
        for (int dy = 0; dy < 2; ++dy)
#pragma unroll
          for (int dx = 0; dx < 2; ++dx) {
            const f2 xs = splat2(xin[dy + ky][dx + kx]);
            acc[0][dy][dx] = fma2(w0, xs, acc[0][dy][dx]);
            acc[1][dy][dx] = fma2(w1p, xs, acc[1][dy][dx]);
          }
      }
  }

  // ---- ReLU + 2x2 pool + spatial partial-sum ----
  const int lane = tid & 63, w = tid >> 6;
#pragma unroll
  for (int p = 0; p < 2; ++p) {
    f2 m01;
    m01.x = fmaxf(fmaxf(fmaxf(acc[p][0][0].x, acc[p][0][1].x),
                        fmaxf(acc[p][1][0].x, acc[p][1][1].x)), 0.f);
    m01.y = fmaxf(fmaxf(fmaxf(acc[p][0][0].y, acc[p][0][1].y),
                        fmaxf(acc[p][1][0].y, acc[p][1][1].y)), 0.f);
#pragma unroll
    for (int off = 32; off > 0; off >>= 1) {
      m01.x += __shfl_down(m01.x, off);
      m01.y += __shfl_down(m01.y, off);
    }
    if (lane == 0) { wred[w][2 * p] = m01.x; wred[w][2 * p + 1] = m01.y; }
  }
  __syncthreads();
  if (tid < 4) {
    float s = wred[0][tid] + wred[1][tid] + wred[2][tid] + wred[3][tid];
    partials[((size_t)b * 4 + q) * 4 + tid] = s;
  }
}

// ---------------------------------------------------------------------------
// K3: feats -> quantum circuit -> batchnorm (over batch=512) -> head.
// Single block, 512 threads; thread = batch element. Shuffle reductions.
// ---------------------------------------------------------------------------
__global__ __launch_bounds__(512) void k3_tail(
    const float* __restrict__ partials, const float* __restrict__ qp,
    const float* __restrict__ gamma, const float* __restrict__ beta,
    const float* __restrict__ hw, const float* __restrict__ hb,
    float* __restrict__ out) {
  __shared__ float wsum[8][8];
  __shared__ float stats[8];
  const int tid = threadIdx.x;  // batch index

  const f4* pp = (const f4*)(partials + tid * 16);
  f4 s0 = pp[0], s1 = pp[1], s2 = pp[2], s3 = pp[3];
  float f[4];
  f[0] = (s0.x + s1.x + s2.x + s3.x) * (1.f / 1024.f);
  f[1] = (s0.y + s1.y + s2.y + s3.y) * (1.f / 1024.f);
  f[2] = (s0.z + s1.z + s2.z + s3.z) * (1.f / 1024.f);
  f[3] = (s0.w + s1.w + s2.w + s3.w) * (1.f / 1024.f);

  float a0r[4], a0i[4], a1r[4], a1i[4];
#pragma unroll
  for (int i = 0; i < 4; ++i) {
    float cy, sy, cx, sx;
    __sincosf(0.5f * f[i], &sy, &cy);
    __sincosf(0.5f * uload(qp + i), &sx, &cx);
    a0r[i] = cx * cy; a0i[i] = -sx * sy;
    a1r[i] = cx * sy; a1i[i] = -sx * cy;
  }

  float pr[16], pi[16];
#pragma unroll
  for (int j = 0; j < 16; ++j) {
    float rr = 1.f, ii = 0.f;
#pragma unroll
    for (int w = 0; w < 4; ++w) {
      int bit = (j >> (3 - w)) & 1;
      float ar = bit ? a1r[w] : a0r[w];
      float ai = bit ? a1i[w] : a0i[w];
      float t = rr * ar - ii * ai;
      ii = rr * ai + ii * ar;
      rr = t;
    }
    pr[j] = rr; pi[j] = ii;
  }

  constexpr int comp[16] = {0, 1, 3, 2, 6, 7, 5, 4, 12, 13, 15, 14, 10, 11, 9, 8};
  float qv[4] = {0.f, 0.f, 0.f, 0.f};
#pragma unroll
  for (int j = 0; j < 16; ++j) {
    int s = comp[j];
    float p = pr[s] * pr[s] + pi[s] * pi[s];
#pragma unroll
    for (int i = 0; i < 4; ++i)
      qv[i] += ((j >> (3 - i)) & 1) ? -p : p;
  }

  float v[8];
#pragma unroll
  for (int i = 0; i < 4; ++i) { v[i] = qv[i]; v[4 + i] = qv[i] * qv[i]; }
#pragma unroll
  for (int k = 0; k < 8; ++k)
#pragma unroll
    for (int off = 32; off > 0; off >>= 1) v[k] += __shfl_down(v[k], off);
  const int lane = tid & 63, w = tid >> 6;
  if (lane == 0) {
#pragma unroll
    for (int k = 0; k < 8; ++k) wsum[w][k] = v[k];
  }
  __syncthreads();
  if (tid < 8) {
    float s = 0.f;
#pragma unroll
    for (int ww = 0; ww < 8; ++ww) s += wsum[ww][tid];
    stats[tid] = s * (1.f / 512.f);
  }
  __syncthreads();

  float nm[4];
#pragma unroll
  for (int i = 0; i < 4; ++i) {
    float mu  = stats[i];
    float var = stats[4 + i] - mu * mu;
    nm[i] = uload(gamma + i) * (qv[i] - mu) * rsqrtf(var + EPS) + uload(beta + i);
  }
#pragma unroll
  for (int k = 0; k < 4; ++k) {
    float o = uload(hb + k);
#pragma unroll
    for (int i = 0; i < 4; ++i) o = fmaf(nm[i], uload(hw + k * 4 + i), o);
    out[tid * 4 + k] = o;
  }
}

extern "C" void kernel_launch(void* const* d_in, const int* in_sizes, int n_in,
                              void* d_out, int out_size, void* d_ws, size_t ws_size,
                              hipStream_t stream) {
  const float* x  = (const float*)d_in[0];
  const float* w1 = (const float*)d_in[1];
  const float* b1 = (const float*)d_in[2];
  const float* w2 = (const float*)d_in[3];
  const float* b2 = (const float*)d_in[4];
  const float* qp = (const float*)d_in[5];
  const float* gm = (const float*)d_in[6];
  const float* bt = (const float*)d_in[7];
  const float* hw = (const float*)d_in[8];
  const float* hb = (const float*)d_in[9];
  float* out = (float*)d_out;

  float* partials = (float*)d_ws;  // 512 * 4 strips * 4 oc floats = 32 KB

  k12_fused<<<512 * 4, 256, 0, stream>>>(x, w1, b1, w2, b2, partials);
  k3_tail<<<1, 512, 0, stream>>>(partials, qp, gm, bt, hw, hb, out);
}